// Round 2
// baseline (24930.919 us; speedup 1.0000x reference)
//
#include <hip/hip_runtime.h>
#include <hip/hip_bf16.h>
#include <math.h>

// ---- problem dims ----
#define Bz  4
#define Sz  1024
#define Dz  768
#define Hz  12
#define HDz 64
#define Lz  4
#define Vz  8000
#define FFz 3072
#define BSz (Bz*Sz)            // 4096 rows
#define EPSz 1e-5f
#define NEG_BIG (-1e30f)

typedef __hip_bfloat16 bf16;

__device__ __forceinline__ float bf2f(unsigned int u) {
    union { unsigned int i; float f; } c; c.i = u << 16; return c.f;
}
__device__ __forceinline__ float tof(bf16 v)  { return __bfloat162float(v); }
__device__ __forceinline__ float tof(float v) { return v; }
__device__ __forceinline__ void stw(bf16* p, float v)  { *p = __float2bfloat16(v); }
__device__ __forceinline__ void stw(float* p, float v) { *p = v; }

// 8-contiguous-element load -> float[8] (16B for bf16, 32B for float)
__device__ __forceinline__ void ld8(const bf16* p, float* o) {
    uint4 u = *(const uint4*)p;
    o[0]=bf2f(u.x&0xffffu); o[1]=bf2f(u.x>>16);
    o[2]=bf2f(u.y&0xffffu); o[3]=bf2f(u.y>>16);
    o[4]=bf2f(u.z&0xffffu); o[5]=bf2f(u.z>>16);
    o[6]=bf2f(u.w&0xffffu); o[7]=bf2f(u.w>>16);
}
__device__ __forceinline__ void ld8(const float* p, float* o) {
    float4 a = *(const float4*)p, b = *(const float4*)(p + 4);
    o[0]=a.x; o[1]=a.y; o[2]=a.z; o[3]=a.w;
    o[4]=b.x; o[5]=b.y; o[6]=b.z; o[7]=b.w;
}

// ---------------- dtype probe: flag=0 -> inputs bf16, flag=1 -> inputs fp32 ----------------
// Reads src_emb (values ~N(0, 0.02)) as raw uint16. If the buffer really is bf16, every
// |value| < 1. If it's fp32 data, the low-half words decode to wild exponents (~25-50%
// with |v|>=1 or NaN).
__global__ void __launch_bounds__(256) detect_kernel(const unsigned short* __restrict__ w,
                                                     int* __restrict__ flag) {
    __shared__ int sh[256];
    int cnt = 0;
    for (int i = threadIdx.x; i < 4096; i += 256) {
        float a = fabsf(bf2f((unsigned int)w[i]));
        if (!(a < 1.0f)) cnt++;   // also counts NaN
    }
    sh[threadIdx.x] = cnt; __syncthreads();
    for (int s = 128; s > 0; s >>= 1) {
        if (threadIdx.x < s) sh[threadIdx.x] += sh[threadIdx.x + s];
        __syncthreads();
    }
    if (threadIdx.x == 0) flag[0] = (sh[0] > 100) ? 1 : 0;
}

// ---------------- embedding: x = emb[tok] + pos (fp32 out) ----------------
template<typename WT>
__global__ void __launch_bounds__(256) embed_kernel(const int* __restrict__ flag, int want,
                                                    const int* __restrict__ tok,
                                                    const WT* __restrict__ emb,
                                                    const WT* __restrict__ pos,
                                                    float* __restrict__ out) {
    if (flag[0] != want) return;
    int idx = blockIdx.x * 256 + threadIdx.x;      // over BSz*Dz (exact multiple)
    int d  = idx % Dz;
    int bs = idx / Dz;
    int s  = bs & (Sz - 1);
    int t  = tok[bs];
    out[idx] = tof(emb[(size_t)t * Dz + d]) + tof(pos[(size_t)s * Dz + d]);
}

// ---------------- layernorm: fp32 in, bf16 out; one block per row ----------------
template<typename WT>
__global__ void __launch_bounds__(256) ln_kernel(const int* __restrict__ flag, int want,
                                                 const float* __restrict__ x,
                                                 const WT* __restrict__ g,
                                                 const WT* __restrict__ b,
                                                 bf16* __restrict__ y) {
    if (flag[0] != want) return;
    int row = blockIdx.x;
    const float* xr = x + (size_t)row * Dz;
    float vals[3];
    float s0 = 0.f, s1 = 0.f;
#pragma unroll
    for (int i = 0; i < 3; i++) {
        float v = xr[threadIdx.x + i * 256];
        vals[i] = v; s0 += v; s1 += v * v;
    }
#pragma unroll
    for (int off = 32; off > 0; off >>= 1) {
        s0 += __shfl_down(s0, off);
        s1 += __shfl_down(s1, off);
    }
    __shared__ float r0[4], r1[4];
    __shared__ float mean_s, inv_s;
    int wid = threadIdx.x >> 6, lane = threadIdx.x & 63;
    if (lane == 0) { r0[wid] = s0; r1[wid] = s1; }
    __syncthreads();
    if (threadIdx.x == 0) {
        float a = r0[0] + r0[1] + r0[2] + r0[3];
        float c = r1[0] + r1[1] + r1[2] + r1[3];
        float mean = a * (1.f / Dz);
        float var  = fmaxf(c * (1.f / Dz) - mean * mean, 0.f);
        mean_s = mean;
        inv_s  = rsqrtf(var + EPSz);
    }
    __syncthreads();
    float mean = mean_s, inv = inv_s;
#pragma unroll
    for (int i = 0; i < 3; i++) {
        int cc = threadIdx.x + i * 256;
        y[(size_t)row * Dz + cc] =
            __float2bfloat16((vals[i] - mean) * inv * tof(g[cc]) + tof(b[cc]));
    }
}

// ---------------- GEMM: C[M,N] = act(A[M,K] @ W[K,N] + bias) ----------------
// A bf16 activations, W/bias WT, fp32 accumulate. 128x128 tile, 256 thr, 8x8/thread.
// OM: 0 = store bf16, 1 = add into fp32, 2 = store WT (final logits)
template<typename WT, bool RELU, int OM>
__global__ void __launch_bounds__(256) gemm_kernel(const int* __restrict__ flag, int want,
                                                   const bf16* __restrict__ A,
                                                   const WT* __restrict__ W,
                                                   const WT* __restrict__ bias,
                                                   bf16* __restrict__ Cb,
                                                   float* __restrict__ Cf,
                                                   WT* __restrict__ Co,
                                                   int M, int N, int K) {
    if (flag[0] != want) return;
    __shared__ float As[16][128];   // [k][m]
    __shared__ float Bs[16][128];   // [k][n]
    const int t  = threadIdx.x;
    const int tx = t & 15, ty = t >> 4;
    const int m0 = blockIdx.y << 7, n0 = blockIdx.x << 7;
    const int ar = t >> 1, ak = (t & 1) << 3;      // A-tile load coords
    const int br = t >> 4, bc = (t & 15) << 3;     // W-tile load coords
    const int wn = n0 + bc;

    float acc[8][8];
#pragma unroll
    for (int i = 0; i < 8; i++)
#pragma unroll
        for (int j = 0; j < 8; j++) acc[i][j] = 0.f;

    for (int k0 = 0; k0 < K; k0 += 16) {
        float av[8];
        ld8(A + (size_t)(m0 + ar) * K + (k0 + ak), av);
#pragma unroll
        for (int i = 0; i < 8; i++) As[ak + i][ar] = av[i];
        float bv[8];
        if (wn + 8 <= N) {
            ld8(W + (size_t)(k0 + br) * N + wn, bv);
        } else {
#pragma unroll
            for (int j = 0; j < 8; j++)
                bv[j] = (wn + j < N) ? tof(W[(size_t)(k0 + br) * N + wn + j]) : 0.f;
        }
        *(float4*)&Bs[br][bc]     = make_float4(bv[0], bv[1], bv[2], bv[3]);
        *(float4*)&Bs[br][bc + 4] = make_float4(bv[4], bv[5], bv[6], bv[7]);
        __syncthreads();
#pragma unroll
        for (int kk = 0; kk < 16; kk++) {
            float a[8], b[8];
            *(float4*)(a)     = *(const float4*)&As[kk][ty << 3];
            *(float4*)(a + 4) = *(const float4*)&As[kk][(ty << 3) + 4];
            *(float4*)(b)     = *(const float4*)&Bs[kk][tx << 3];
            *(float4*)(b + 4) = *(const float4*)&Bs[kk][(tx << 3) + 4];
#pragma unroll
            for (int i = 0; i < 8; i++)
#pragma unroll
                for (int j = 0; j < 8; j++)
                    acc[i][j] = fmaf(a[i], b[j], acc[i][j]);
        }
        __syncthreads();
    }
#pragma unroll
    for (int j = 0; j < 8; j++) {
        int n = n0 + (tx << 3) + j;
        if (n >= N) continue;
        float bsv = tof(bias[n]);
#pragma unroll
        for (int i = 0; i < 8; i++) {
            int m = m0 + (ty << 3) + i;
            float v = acc[i][j] + bsv;
            if (RELU) v = fmaxf(v, 0.f);
            if (OM == 0)      Cb[(size_t)m * N + n] = __float2bfloat16(v);
            else if (OM == 1) Cf[(size_t)m * N + n] += v;
            else              stw(Co + ((size_t)m * N + n), v);
        }
    }
}

// ---------------- fused attention: 1 wave per (b,h,q-row); bf16 q/k/v/o ----------------
template<int CAUSAL>
__global__ void __launch_bounds__(256) attn_kernel(const int* __restrict__ flag, int want,
                                                   const bf16* __restrict__ Q,
                                                   const bf16* __restrict__ Kt,
                                                   const bf16* __restrict__ Vt,
                                                   bf16* __restrict__ O) {
    if (flag[0] != want) return;
    __shared__ float qs[4][HDz];
    __shared__ float ps[4][Sz];
    int wid = threadIdx.x >> 6, lane = threadIdx.x & 63;
    int gw = blockIdx.x * 4 + wid;          // over B*H*S
    int qrow = gw & (Sz - 1);
    int bh = gw >> 10;                      // / Sz
    int h = bh % Hz, b = bh / Hz;
    const size_t hoff = (size_t)h * HDz;

    qs[wid][lane] = tof(Q[((size_t)(b * Sz + qrow)) * Dz + hoff + lane]);
    __syncthreads();

    const bf16* kbase = Kt + (size_t)b * Sz * Dz + hoff;
    float sc[16];
    float mx = NEG_BIG;
#pragma unroll 1
    for (int kk = 0; kk < 16; kk++) {
        int kr = (kk << 6) + lane;
        const bf16* krow = kbase + (size_t)kr * Dz;
        float dot = 0.f;
#pragma unroll
        for (int j8 = 0; j8 < 8; j8++) {
            float kv[8];
            ld8(krow + (j8 << 3), kv);
#pragma unroll
            for (int i = 0; i < 8; i++) dot = fmaf(qs[wid][(j8 << 3) + i], kv[i], dot);
        }
        dot *= 0.125f;                      // HD^-0.5
        if (CAUSAL && kr > qrow) dot = NEG_BIG;
        sc[kk] = dot;
        mx = fmaxf(mx, dot);
    }
#pragma unroll
    for (int off = 32; off > 0; off >>= 1) mx = fmaxf(mx, __shfl_down(mx, off));
    mx = __shfl(mx, 0);
    float sum = 0.f;
#pragma unroll
    for (int kk = 0; kk < 16; kk++) { float e = __expf(sc[kk] - mx); sc[kk] = e; sum += e; }
#pragma unroll
    for (int off = 32; off > 0; off >>= 1) sum += __shfl_down(sum, off);
    sum = __shfl(sum, 0);
    float inv = 1.f / sum;
#pragma unroll
    for (int kk = 0; kk < 16; kk++) ps[wid][(kk << 6) + lane] = sc[kk] * inv;
    __syncthreads();

    const bf16* vbase = Vt + (size_t)b * Sz * Dz + hoff + lane;
    float o = 0.f;
#pragma unroll 8
    for (int k2 = 0; k2 < Sz; k2++) o = fmaf(ps[wid][k2], tof(vbase[(size_t)k2 * Dz]), o);
    O[((size_t)(b * Sz + qrow)) * Dz + hoff + lane] = __float2bfloat16(o);
}

// ---------------- whole network for one dtype-world ----------------
template<typename WT>
static void run_net(void* const* d_in, int want, int* flag,
                    float* x, bf16* xn, bf16* memb,
                    bf16* q, bf16* k, bf16* v, bf16* ao, bf16* hbuf,
                    WT* out, hipStream_t stream) {
    const int* src    = (const int*)d_in[0];
    const int* target = (const int*)d_in[2];
    const WT* src_emb = (const WT*)d_in[4];
    const WT* tgt_emb = (const WT*)d_in[5];
    const WT* pos_emb = (const WT*)d_in[6];
    const WT* eaw = (const WT*)d_in[7];
    const WT* eab = (const WT*)d_in[8];
    const WT* elg = (const WT*)d_in[9];
    const WT* elb = (const WT*)d_in[10];
    const WT* ew1 = (const WT*)d_in[11];
    const WT* eb1 = (const WT*)d_in[12];
    const WT* ew2 = (const WT*)d_in[13];
    const WT* eb2 = (const WT*)d_in[14];
    const WT* eng = (const WT*)d_in[15];
    const WT* enb = (const WT*)d_in[16];
    const WT* daw = (const WT*)d_in[17];
    const WT* dab = (const WT*)d_in[18];
    const WT* dlg = (const WT*)d_in[19];
    const WT* dlb = (const WT*)d_in[20];
    const WT* dw1 = (const WT*)d_in[21];
    const WT* db1 = (const WT*)d_in[22];
    const WT* dw2 = (const WT*)d_in[23];
    const WT* db2 = (const WT*)d_in[24];
    const WT* dng = (const WT*)d_in[25];
    const WT* dnb = (const WT*)d_in[26];
    const WT* outw = (const WT*)d_in[27];
    const WT* outb = (const WT*)d_in[28];

    const size_t DD = (size_t)Dz * Dz;
    dim3 blk(256);
    // mode: 0 store-bf16, 1 relu-store-bf16, 2 add-into-f32, 3 store-WT
    auto gemm = [&](const bf16* A, const WT* W, const WT* bias,
                    bf16* CbP, float* CfP, WT* CoP, int M, int N, int K, int mode) {
        dim3 grid((N + 127) / 128, M / 128);
        if (mode == 0)
            gemm_kernel<WT, false, 0><<<grid, blk, 0, stream>>>(flag, want, A, W, bias, CbP, nullptr, nullptr, M, N, K);
        else if (mode == 1)
            gemm_kernel<WT, true, 0><<<grid, blk, 0, stream>>>(flag, want, A, W, bias, CbP, nullptr, nullptr, M, N, K);
        else if (mode == 2)
            gemm_kernel<WT, false, 1><<<grid, blk, 0, stream>>>(flag, want, A, W, bias, nullptr, CfP, nullptr, M, N, K);
        else
            gemm_kernel<WT, false, 2><<<grid, blk, 0, stream>>>(flag, want, A, W, bias, nullptr, nullptr, CoP, M, N, K);
    };

    // ================= encoder =================
    embed_kernel<WT><<<BSz * Dz / 256, blk, 0, stream>>>(flag, want, src, src_emb, pos_emb, x);
    for (int l = 0; l < Lz; l++) {
        const WT* w  = eaw + (size_t)l * 4 * DD;
        const WT* bb = eab + (size_t)l * 4 * Dz;
        ln_kernel<WT><<<BSz, blk, 0, stream>>>(flag, want, x, elg + (size_t)(l * 2) * Dz, elb + (size_t)(l * 2) * Dz, xn);
        gemm(xn, w + 0 * DD, bb + 0 * Dz, q, nullptr, nullptr, BSz, Dz, Dz, 0);
        gemm(xn, w + 1 * DD, bb + 1 * Dz, k, nullptr, nullptr, BSz, Dz, Dz, 0);
        gemm(xn, w + 2 * DD, bb + 2 * Dz, v, nullptr, nullptr, BSz, Dz, Dz, 0);
        attn_kernel<0><<<Bz * Hz * Sz / 4, blk, 0, stream>>>(flag, want, q, k, v, ao);
        gemm(ao, w + 3 * DD, bb + 3 * Dz, nullptr, x, nullptr, BSz, Dz, Dz, 2);
        ln_kernel<WT><<<BSz, blk, 0, stream>>>(flag, want, x, elg + (size_t)(l * 2 + 1) * Dz, elb + (size_t)(l * 2 + 1) * Dz, xn);
        gemm(xn, ew1 + (size_t)l * Dz * FFz, eb1 + (size_t)l * FFz, hbuf, nullptr, nullptr, BSz, FFz, Dz, 1);
        gemm(hbuf, ew2 + (size_t)l * FFz * Dz, eb2 + (size_t)l * Dz, nullptr, x, nullptr, BSz, Dz, FFz, 2);
    }
    ln_kernel<WT><<<BSz, blk, 0, stream>>>(flag, want, x, eng, enb, memb);

    // ================= decoder =================
    embed_kernel<WT><<<BSz * Dz / 256, blk, 0, stream>>>(flag, want, target, tgt_emb, pos_emb, x);
    for (int l = 0; l < Lz; l++) {
        const WT* w  = daw + (size_t)l * 8 * DD;
        const WT* bb = dab + (size_t)l * 8 * Dz;
        // self-attention (causal)
        ln_kernel<WT><<<BSz, blk, 0, stream>>>(flag, want, x, dlg + (size_t)(l * 3) * Dz, dlb + (size_t)(l * 3) * Dz, xn);
        gemm(xn, w + 0 * DD, bb + 0 * Dz, q, nullptr, nullptr, BSz, Dz, Dz, 0);
        gemm(xn, w + 1 * DD, bb + 1 * Dz, k, nullptr, nullptr, BSz, Dz, Dz, 0);
        gemm(xn, w + 2 * DD, bb + 2 * Dz, v, nullptr, nullptr, BSz, Dz, Dz, 0);
        attn_kernel<1><<<Bz * Hz * Sz / 4, blk, 0, stream>>>(flag, want, q, k, v, ao);
        gemm(ao, w + 3 * DD, bb + 3 * Dz, nullptr, x, nullptr, BSz, Dz, Dz, 2);
        // cross-attention
        ln_kernel<WT><<<BSz, blk, 0, stream>>>(flag, want, x, dlg + (size_t)(l * 3 + 1) * Dz, dlb + (size_t)(l * 3 + 1) * Dz, xn);
        gemm(xn,   w + 4 * DD, bb + 4 * Dz, q, nullptr, nullptr, BSz, Dz, Dz, 0);
        gemm(memb, w + 5 * DD, bb + 5 * Dz, k, nullptr, nullptr, BSz, Dz, Dz, 0);
        gemm(memb, w + 6 * DD, bb + 6 * Dz, v, nullptr, nullptr, BSz, Dz, Dz, 0);
        attn_kernel<0><<<Bz * Hz * Sz / 4, blk, 0, stream>>>(flag, want, q, k, v, ao);
        gemm(ao, w + 7 * DD, bb + 7 * Dz, nullptr, x, nullptr, BSz, Dz, Dz, 2);
        // ffn
        ln_kernel<WT><<<BSz, blk, 0, stream>>>(flag, want, x, dlg + (size_t)(l * 3 + 2) * Dz, dlb + (size_t)(l * 3 + 2) * Dz, xn);
        gemm(xn, dw1 + (size_t)l * Dz * FFz, db1 + (size_t)l * FFz, hbuf, nullptr, nullptr, BSz, FFz, Dz, 1);
        gemm(hbuf, dw2 + (size_t)l * FFz * Dz, db2 + (size_t)l * Dz, nullptr, x, nullptr, BSz, Dz, FFz, 2);
    }
    ln_kernel<WT><<<BSz, blk, 0, stream>>>(flag, want, x, dng, dnb, xn);

    // ================= output projection =================
    gemm(xn, outw, outb, nullptr, nullptr, out, BSz, Vz, Dz, 3);
}

// ---------------- launcher ----------------
extern "C" void kernel_launch(void* const* d_in, const int* in_sizes, int n_in,
                              void* d_out, int out_size, void* d_ws, size_t ws_size,
                              hipStream_t stream) {
    const size_t SD = (size_t)BSz * Dz;        // 3,145,728 elements
    char* wsb = (char*)d_ws;
    int*   flag = (int*)wsb;                                   // 256 B reserved
    float* x    = (float*)(wsb + 256);                         // SD fp32
    bf16*  xn   = (bf16*)(wsb + 256 + SD * 4);                 // SD bf16
    bf16*  memb = xn + SD;                                     // SD bf16
    bf16*  big  = memb + SD;                                   // 4*SD bf16
    bf16 *q = big, *k = big + SD, *v = big + 2 * SD, *ao = big + 3 * SD;
    bf16* hbuf = big;                                          // BSz*FFz == 4*SD, aliases q/k/v/ao
    // total ws use: 256 + 4*SD + 2*2*SD + 2*4*SD = ~50.4 MB

    detect_kernel<<<1, 256, 0, stream>>>((const unsigned short*)d_in[4], flag);
    run_net<bf16 >(d_in, 0, flag, x, xn, memb, q, k, v, ao, hbuf, (bf16*)d_out, stream);
    run_net<float>(d_in, 1, flag, x, xn, memb, q, k, v, ao, hbuf, (float*)d_out, stream);
}